// Round 13
// baseline (1046.431 us; speedup 1.0000x reference)
//
#include <hip/hip_runtime.h>
#include <cstdint>

typedef __attribute__((ext_vector_type(8))) short short8;
typedef __attribute__((ext_vector_type(4))) float f32x4;
typedef __attribute__((ext_vector_type(4))) unsigned u32x4;

#define R_DIM 1024
#define KE    1056      // 1024 state + 8 x + 24 zero pad
#define T_LEN 65536
#define CCH   1024      // chunks
#define LCH   64        // real steps per chunk
#define WARM  12        // warmup steps (validated R9-R11: absmax 0.0307)
#define STEPS (WARM + LCH)   // 76
#define NGRP  32        // groups, 32 cols each
#define WGC   32
#define RWG   8         // row-WGs per group (128 rows each)

static __device__ __forceinline__ unsigned short f2bf(float f){
  unsigned u = __builtin_bit_cast(unsigned, f);
  u += 0x7fffu + ((u >> 16) & 1u);
  return (unsigned short)(u >> 16);
}
static __device__ __forceinline__ float fast_tanh(float x){
  float e = __expf(2.0f * x);          // inf/0 saturate correctly to +/-1
  return 1.0f - 2.0f / (e + 1.0f);
}

// ---- prep: W_ext = [W_res | W_in | 0] in bf16, row-major [1024][1056] ----
__global__ void k_build_wext(const float* __restrict__ Wres,
                             const float* __restrict__ Win,
                             short* __restrict__ Wext){
  int idx = blockIdx.x * 256 + threadIdx.x;       // 1024*1056 = 4224*256
  int r = idx / KE, k = idx % KE;
  float v = 0.0f;
  if (k < 1024)      v = Wres[(size_t)r * 1024 + k];
  else if (k < 1032) v = Win[r * 8 + (k - 1024)];
  Wext[idx] = (short)f2bf(v);
}

// ---- prep: zero state region [0,1024) of each chunk's initial-read row ----
__global__ void k_zero_init(short* __restrict__ base, size_t rowstride){
  int idx = blockIdx.x * 256 + threadIdx.x;   // 1024 rows x 512 dwords = 2048 blocks
  int c = idx >> 9, d = idx & 511;
  ((unsigned*)(base + (size_t)c * rowstride))[d] = 0u;
}

// ---- prep: x-slot of each chunk's initial row, zero 2048 wave-flags ----
__global__ void k_init_x(const float* __restrict__ in, short* __restrict__ x0,
                         size_t rowstride, unsigned* __restrict__ cnt){
  int c = blockIdx.x * 256 + threadIdx.x;
  if (c < 2048) cnt[c] = 0u;                  // 32 groups x 64 wave-flags
  if (c < CCH){
    int t0 = c * LCH - WARM;
    uint4 xv = {0,0,0,0};
    if (t0 >= 0){
      const float4 A4 = *(const float4*)(in + (size_t)t0 * 8);
      const float4 B4 = *(const float4*)(in + (size_t)t0 * 8 + 4);
      xv.x = f2bf(A4.x) | ((unsigned)f2bf(A4.y) << 16);
      xv.y = f2bf(A4.z) | ((unsigned)f2bf(A4.w) << 16);
      xv.z = f2bf(B4.x) | ((unsigned)f2bf(B4.y) << 16);
      xv.w = f2bf(B4.z) | ((unsigned)f2bf(B4.w) << 16);
    }
    *(uint4*)(x0 + (size_t)c * rowstride) = xv;
  }
}

// ---- output rows 1024..1031 = inputs^T (exact fp32 copy) ----
__global__ void k_xrows(const float* __restrict__ in, float* __restrict__ out){
  int t = blockIdx.x * 256 + threadIdx.x;
  const float4 a = *(const float4*)(in + (size_t)t * 8);
  const float4 b = *(const float4*)(in + (size_t)t * 8 + 4);
  out[(size_t)(R_DIM + 0) * T_LEN + t] = a.x;
  out[(size_t)(R_DIM + 1) * T_LEN + t] = a.y;
  out[(size_t)(R_DIM + 2) * T_LEN + t] = a.z;
  out[(size_t)(R_DIM + 3) * T_LEN + t] = a.w;
  out[(size_t)(R_DIM + 4) * T_LEN + t] = b.x;
  out[(size_t)(R_DIM + 5) * T_LEN + t] = b.y;
  out[(size_t)(R_DIM + 6) * T_LEN + t] = b.z;
  out[(size_t)(R_DIM + 7) * T_LEN + t] = b.w;
}

// ---- hist[t][r] (bf16) -> out[r][t] (f32), tiled transpose ----
__global__ void k_transpose(const short* __restrict__ hist, float* __restrict__ out){
  __shared__ float tile[64][65];
  const int t0 = blockIdx.x * 64;
  const int r0 = blockIdx.y * 64;
  for (int it = 0; it < 2; ++it){
    int id = it * 256 + threadIdx.x;     // 512 chunks of 8 bf16
    int tr = id >> 3;
    int c8 = (id & 7) * 8;
    short8 v = *(const short8*)(hist + (size_t)(t0 + tr) * KE + r0 + c8);
    #pragma unroll
    for (int j = 0; j < 8; ++j){
      unsigned u = ((unsigned)(unsigned short)v[j]) << 16;
      tile[tr][c8 + j] = __builtin_bit_cast(float, u);
    }
  }
  __syncthreads();
  #pragma unroll
  for (int p = 0; p < 16; ++p){
    int rr = (threadIdx.x >> 6) + p * 4;
    int tc = threadIdx.x & 63;
    out[(size_t)(r0 + rr) * T_LEN + t0 + tc] = tile[tc][rr];
  }
}

#define MFMA16(a,b,c) __builtin_amdgcn_mfma_f32_16x16x32_bf16(a,b,c,0,0,0)

// gate piece p on its producer's 8 wave-flags (spin only if ballot miss),
// then issue its 16B load. All waits are vmcnt(0) (robust to compiler VMEM).
#define GATE_ISSUE(p) do{ \
  if (k > 0 && (((rm >> (8*(p))) & 0xFFull) != 0xFFull)){ \
    const unsigned* fq = gflags + 8*(p) + (lane & 7); \
    int guard = 0; \
    for(;;){ \
      unsigned pv; \
      asm volatile("global_load_dword %0, %1, off sc0 sc1\n\t" \
                   "s_waitcnt vmcnt(0)" : "=v"(pv) : "v"(fq) : "memory"); \
      unsigned long long rm2 = __ballot((int)(pv >= (unsigned)k)); \
      if ((rm2 & 0xFFull) == 0xFFull || ++guard > 1000000) break; \
      __builtin_amdgcn_s_sleep(1); \
    } \
  } \
  { const char* pa_ = spb + (p) * 256; \
    if (coh) asm volatile("global_load_dwordx4 %0, %1, off sc0 sc1" \
                          : "=&v"(pr##p) : "v"(pa_) : "memory"); \
    else     asm volatile("global_load_dwordx4 %0, %1, off" \
                          : "=&v"(pr##p) : "v"(pa_) : "memory"); } \
}while(0)

#define LDSW8(p, dst) do { \
  *(u32x4*)(dst + ((skb0 +    0) ^ sswz)) = p##0; \
  *(u32x4*)(dst + ((skb0 +  256) ^ sswz)) = p##1; \
  *(u32x4*)(dst + ((skb0 +  512) ^ sswz)) = p##2; \
  *(u32x4*)(dst + ((skb0 +  768) ^ sswz)) = p##3; \
  *(u32x4*)(dst + ((skb0 + 1024) ^ sswz)) = p##4; \
  *(u32x4*)(dst + ((skb0 + 1280) ^ sswz)) = p##5; \
  *(u32x4*)(dst + ((skb0 + 1536) ^ sswz)) = p##6; \
  *(u32x4*)(dst + ((skb0 + 1792) ^ sswz)) = p##7; } while(0)

// ---- main: 256 WGs x 512 thr (1 WG/CU); WG = 128 rows x 32 cols.
// PER-WAVE flags (64/group): each wave drains its own stores then signals;
// consumers read all 64 flags with ONE ballot load. Piece p (256B/col,
// k-range [128p,128p+128)) gated on producer-WG p's 8 wave-flags -> gated
// issue streams loads while stragglers are spun. Single absolute vmcnt(0)
// + sched_barrier(0) before consume (R12 lesson: counted vmcnt breaks when
// the compiler interleaves its own VMEM, e.g. A-frag reloads; MFMA can hoist
// past inline-asm waits per rule #18). waves_per_eu(2,2): allow 256 VGPRs so
// the 136 A-frag regs can actually be resident (VGPR_Count 116-128 in R3-R11
// proves they never were). All cross-WG protocol sc0 sc1; write-once rows
// (k>WARM+2) staged with plain cached loads (R7-proven).
template<bool HIST>
__global__ __attribute__((amdgpu_flat_work_group_size(512,512), amdgpu_waves_per_eu(2,2)))
void k_esn(const float* __restrict__ inputs, const short* __restrict__ Wext,
           short* __restrict__ S0, short* __restrict__ S1,
           short* __restrict__ hist, unsigned* __restrict__ cnt,
           float* __restrict__ out)
{
  __shared__ __align__(16) char lds[65536];   // 32 cols x 2048B, XOR-swizzled
  const int tid  = threadIdx.x;
  const int g    = blockIdx.x & (NGRP - 1);
  const int rwg  = blockIdx.x >> 5;           // bid=rwg*32+g -> group on one XCD
  const int wv   = tid >> 6;
  const int lane = tid & 63;
  const int l15  = lane & 15, l4 = lane >> 4;
  const int hi   = wv & 1;
  const int rbase = rwg * 128 + (wv >> 1) * 32;
  const int colbase = g * WGC;
  unsigned* gflags = cnt + g * 64;            // 64 wave-flags per group

  auto browf = [&](int col, int k) -> const short* {
    if (HIST){
      size_t row = (k <= WARM) ? ((size_t)col * LCH + ((k + 1) & 1))
                               : ((size_t)col * LCH + (size_t)(k - WARM) - 1);
      return hist + row * KE;
    }
    return ((k & 1) ? S1 : S0) + (size_t)col * KE;
  };
  auto wrowf = [&](int col, int k) -> short* {
    if (HIST){
      size_t row = (k < WARM) ? ((size_t)col * LCH + (k & 1))
                              : ((size_t)col * LCH + (size_t)(k - WARM));
      return hist + row * KE;
    }
    return ((k & 1) ? S0 : S1) + (size_t)col * KE;
  };

  // ---- loop-invariant A fragments (R11's proven contiguous K-split) ----
  const int NA = hi ? 16 : 17;
  const int KB = hi ? 17 : 0;
  const int NL = hi ? 15 : 17;
  short8 a0[17], a1[17];
  {
    const short* abase = Wext + (size_t)(rbase + l15) * KE + l4 * 8;
    #pragma unroll
    for (int i = 0; i < 17; ++i){
      if (i < NA){
        const short* ap = abase + (KB + i) * 32;
        a0[i] = *(const short8*)ap;
        a1[i] = *(const short8*)(ap + (size_t)16 * KE);
      }
    }
  }

  const int scol = tid >> 4;                  // owned col (0..31)
  const int skb0 = (tid & 15) << 4;           // 16B slot within a 256B piece
  const int sswz = (scol & 7) << 4;
  const int colb0 = l15 * 2048;
  const int bswz  = (l15 & 7) << 4;
  const int l4b   = l4 * 16;
  const int xsw = (lane * 16) ^ ((lane >> 3) << 4);

  for (int k = 0; k < STEPS; ++k){
    const bool coh = (!HIST) || (k <= WARM + 2);
    const char* spb = (const char*)browf(colbase + scol, k) + skb0;

    // ---- one ballot over all 64 producer-wave flags ----
    unsigned long long rm = ~0ull;
    if (k > 0){
      unsigned fl;
      const unsigned* fp = gflags + lane;
      asm volatile("global_load_dword %0, %1, off sc0 sc1\n\t"
                   "s_waitcnt vmcnt(0)" : "=v"(fl) : "v"(fp) : "memory");
      rm = __ballot((int)(fl >= (unsigned)k));
    }

    // ---- gated piece issue (loads fly while stragglers are spun) ----
    u32x4 pr0, pr1, pr2, pr3, pr4, pr5, pr6, pr7;
    GATE_ISSUE(0);
    // K-ext tail (x written by WG0/wave0 = flag 0, covered by piece-0 gate)
    unsigned long long t00 = 0, t01 = 0, t10 = 0, t11 = 0;
    if (hi){
      const char* tp0 = (const char*)(browf(colbase + l15, k) + 1024 + l4 * 8);
      const char* tp1 = (const char*)(browf(colbase + 16 + l15, k) + 1024 + l4 * 8);
      asm volatile(
        "global_load_dwordx2 %0, %4, off sc0 sc1\n\t"
        "global_load_dwordx2 %1, %4, off offset:8 sc0 sc1\n\t"
        "global_load_dwordx2 %2, %5, off sc0 sc1\n\t"
        "global_load_dwordx2 %3, %5, off offset:8 sc0 sc1"
        : "=&v"(t00),"=&v"(t01),"=&v"(t10),"=&v"(t11)
        : "v"(tp0), "v"(tp1) : "memory");
    }
    GATE_ISSUE(1); GATE_ISSUE(2); GATE_ISSUE(3);
    GATE_ISSUE(4); GATE_ISSUE(5); GATE_ISSUE(6); GATE_ISSUE(7);

    // ---- single absolute drain; fence against MFMA/LDS-store hoisting ----
    asm volatile("s_waitcnt vmcnt(0)" ::: "memory");
    __builtin_amdgcn_sched_barrier(0);

    LDSW8(pr, (&lds[scol * 2048]));
    __syncthreads();                          // B: tile staged

    // ---- MFMA K-loop (verbatim R11, proven) ----
    f32x4 acc00 = {0,0,0,0}, acc01 = {0,0,0,0}, acc10 = {0,0,0,0}, acc11 = {0,0,0,0};
    #pragma unroll
    for (int i = 0; i < 17; ++i){
      if (i < NL){
        int kb = (KB + i) * 64 + l4b;
        const short8 b0 = *(const short8*)(&lds[colb0 + (kb ^ bswz)]);
        const short8 b1 = *(const short8*)(&lds[colb0 + 32768 + (kb ^ bswz)]);
        acc00 = MFMA16(a0[i], b0, acc00);
        acc01 = MFMA16(a0[i], b1, acc01);
        acc10 = MFMA16(a1[i], b0, acc10);
        acc11 = MFMA16(a1[i], b1, acc11);
      }
    }
    if (hi){   // kk=32 tail: B from registers (pad nulled by Wext zeros)
      u32x4 v0; v0.x=(unsigned)t00; v0.y=(unsigned)(t00>>32); v0.z=(unsigned)t01; v0.w=(unsigned)(t01>>32);
      u32x4 v1; v1.x=(unsigned)t10; v1.y=(unsigned)(t10>>32); v1.z=(unsigned)t11; v1.w=(unsigned)(t11>>32);
      const short8 b0 = __builtin_bit_cast(short8, v0);
      const short8 b1 = __builtin_bit_cast(short8, v1);
      acc00 = MFMA16(a0[15], b0, acc00);
      acc01 = MFMA16(a0[15], b1, acc01);
      acc10 = MFMA16(a1[15], b0, acc10);
      acc11 = MFMA16(a1[15], b1, acc11);
    }

    // ---- cross-pair K-reduction via LDS ----
    __syncthreads();                          // C
    {
      *(f32x4*)(&lds[wv * 1024 + xsw])        = hi ? acc00 : acc10;
      *(f32x4*)(&lds[8192 + wv * 1024 + xsw]) = hi ? acc01 : acc11;
    }
    __syncthreads();                          // D
    f32x4 p0 = *(const f32x4*)(&lds[(wv ^ 1) * 1024 + xsw]);
    f32x4 p1 = *(const f32x4*)(&lds[8192 + (wv ^ 1) * 1024 + xsw]);
    __syncthreads();                          // E: LDS free for next step

    // ---- per-wave finish: tanh, stores, own drain, own flag ----
    {
      f32x4 f0 = (hi ? acc10 : acc00) + p0;
      f32x4 f1 = (hi ? acc11 : acc01) + p1;
      const int rowb = rbase + hi * 16 + l4 * 4;
      #pragma unroll
      for (int ct = 0; ct < 2; ++ct){
        f32x4 z = ct ? f1 : f0;
        float s0 = fast_tanh(z[0]), s1 = fast_tanh(z[1]);
        float s2 = fast_tanh(z[2]), s3 = fast_tanh(z[3]);
        unsigned long long pk = (unsigned long long)f2bf(s0)
          | ((unsigned long long)f2bf(s1) << 16)
          | ((unsigned long long)f2bf(s2) << 32)
          | ((unsigned long long)f2bf(s3) << 48);
        int col = colbase + ct * 16 + l15;
        short* wp = wrowf(col, k) + rowb;
        asm volatile("global_store_dwordx2 %0, %1, off sc0 sc1"
                     :: "v"(wp), "v"(pk) : "memory");
        if (!HIST && k >= WARM){
          int tk = col * LCH + k - WARM;
          float* op = out + (size_t)rowb * T_LEN + tk;
          op[0] = s0; op[(size_t)T_LEN] = s1;
          op[(size_t)2 * T_LEN] = s2; op[(size_t)3 * T_LEN] = s3;
        }
      }
      // x for next step (wave 0 of WG rwg==0)
      if (rwg == 0 && tid < WGC && (k + 1) < STEPS){
        int col = colbase + tid;
        short* xr = wrowf(col, k) + 1024;
        int tn = col * LCH + (k + 1) - WARM;
        u32x4 xv = {0,0,0,0};
        if (tn >= 0){
          const float4 A4 = *(const float4*)(inputs + (size_t)tn * 8);
          const float4 B4 = *(const float4*)(inputs + (size_t)tn * 8 + 4);
          xv.x = f2bf(A4.x) | ((unsigned)f2bf(A4.y) << 16);
          xv.y = f2bf(A4.z) | ((unsigned)f2bf(A4.w) << 16);
          xv.z = f2bf(B4.x) | ((unsigned)f2bf(B4.y) << 16);
          xv.w = f2bf(B4.z) | ((unsigned)f2bf(B4.w) << 16);
        }
        asm volatile("global_store_dwordx4 %0, %1, off sc0 sc1"
                     :: "v"(xr), "v"(xv) : "memory");
      }
      // own-wave drain to coherence point, then own-wave flag (no WG barrier)
      asm volatile("s_waitcnt vmcnt(0)" ::: "memory");
      if (lane == 0 && (k + 1) < STEPS){
        unsigned* fw = gflags + rwg * 8 + wv;
        unsigned fv = (unsigned)(k + 1);
        asm volatile("global_store_dword %0, %1, off sc0 sc1"
                     :: "v"(fw), "v"(fv) : "memory");
      }
    }
  }
}

extern "C" void kernel_launch(void* const* d_in, const int* in_sizes, int n_in,
                              void* d_out, int out_size, void* d_ws, size_t ws_size,
                              hipStream_t stream)
{
  (void)in_sizes; (void)n_in; (void)out_size;
  const float* inputs = (const float*)d_in[0];
  const float* Win    = (const float*)d_in[1];
  const float* Wres   = (const float*)d_in[2];
  float* out = (float*)d_out;
  char* ws = (char*)d_ws;

  short*    Wext = (short*)(ws);                       // 2,162,688 B
  unsigned* cnt  = (unsigned*)(ws + 2162688);          // 8,192 B: 32 groups x 64 flags
  char*     data = ws + 2170880;
  short*    hist = (short*)data;                       // 65536*1056*2 = 138,412,032 B
  short*    S0   = (short*)data;                       // !HIST: 1024*1056*2 B
  short*    S1   = (short*)(data + 2162688);
  const bool hist_ok = ws_size >= (2170880ull + 138412032ull);

  hipLaunchKernelGGL(k_build_wext, dim3(4224), dim3(256), 0, stream, Wres, Win, Wext);
  hipLaunchKernelGGL(k_xrows,      dim3(256),  dim3(256), 0, stream, inputs, out);
  if (hist_ok){
    hipLaunchKernelGGL(k_zero_init, dim3(2048), dim3(256), 0, stream,
                       hist + KE, (size_t)LCH * KE);
    hipLaunchKernelGGL(k_init_x,    dim3(8),    dim3(256), 0, stream,
                       inputs, hist + KE + 1024, (size_t)LCH * KE, cnt);
    hipLaunchKernelGGL((k_esn<true>),  dim3(RWG * NGRP), dim3(512), 0, stream,
                       inputs, Wext, S0, S1, hist, cnt, out);
    hipLaunchKernelGGL(k_transpose, dim3(1024, 16), dim3(256), 0, stream, hist, out);
  } else {
    hipLaunchKernelGGL(k_zero_init, dim3(2048), dim3(256), 0, stream,
                       S0, (size_t)KE);
    hipLaunchKernelGGL(k_init_x,    dim3(8),    dim3(256), 0, stream,
                       inputs, S0 + 1024, (size_t)KE, cnt);
    hipLaunchKernelGGL((k_esn<false>), dim3(RWG * NGRP), dim3(512), 0, stream,
                       inputs, Wext, S0, S1, hist, cnt, out);
  }
}

// Round 14
// 535.969 us; speedup vs baseline: 1.9524x; 1.9524x over previous
//
#include <hip/hip_runtime.h>
#include <cstdint>

typedef __attribute__((ext_vector_type(8))) short short8;
typedef __attribute__((ext_vector_type(4))) float f32x4;
typedef __attribute__((ext_vector_type(4))) unsigned u32x4;

#define R_DIM 1024
#define KE    1056      // 1024 state + 8 x + 24 zero pad
#define T_LEN 65536
#define CCH   2048      // chunks
#define LCH   32        // real steps per chunk
#define WARM  12        // warmup steps (validated R9-R13: absmax 0.0307)
#define STEPS (WARM + LCH)   // 44
#define NGRP  32        // groups, 64 cols each
#define WGC   64        // cols per WG (single phase)
#define RWG   8         // row-WGs per group (128 rows each)
#define LDSB  131072    // 64 cols x 2048B staged B (dynamic LDS)

static __device__ __forceinline__ unsigned short f2bf(float f){
  unsigned u = __builtin_bit_cast(unsigned, f);
  u += 0x7fffu + ((u >> 16) & 1u);
  return (unsigned short)(u >> 16);
}
static __device__ __forceinline__ float fast_tanh(float x){
  float e = __expf(2.0f * x);          // inf/0 saturate correctly to +/-1
  return 1.0f - 2.0f / (e + 1.0f);
}

// ---- prep: W_ext = [W_res | W_in | 0] in bf16, row-major [1024][1056] ----
__global__ void k_build_wext(const float* __restrict__ Wres,
                             const float* __restrict__ Win,
                             short* __restrict__ Wext){
  int idx = blockIdx.x * 256 + threadIdx.x;       // 1024*1056 = 4224*256
  int r = idx / KE, k = idx % KE;
  float v = 0.0f;
  if (k < 1024)      v = Wres[(size_t)r * 1024 + k];
  else if (k < 1032) v = Win[r * 8 + (k - 1024)];
  Wext[idx] = (short)f2bf(v);
}

// ---- prep: zero state region [0,1024) of each chunk's initial-read row ----
__global__ void k_zero_init(short* __restrict__ base, size_t rowstride){
  int idx = blockIdx.x * 256 + threadIdx.x;   // 2048 rows x 512 dwords = 4096 blocks
  int c = idx >> 9, d = idx & 511;
  ((unsigned*)(base + (size_t)c * rowstride))[d] = 0u;
}

// ---- prep: x-slot of each chunk's initial row, zero flags ----
__global__ void k_init_x(const float* __restrict__ in, short* __restrict__ x0,
                         size_t rowstride, unsigned* __restrict__ cnt){
  int c = blockIdx.x * 256 + threadIdx.x;
  if (c < NGRP * 16) cnt[c] = 0u;             // 32 groups x 8 flags (16-dw stride)
  if (c < CCH){
    int t0 = c * LCH - WARM;
    uint4 xv = {0,0,0,0};
    if (t0 >= 0){
      const float4 A4 = *(const float4*)(in + (size_t)t0 * 8);
      const float4 B4 = *(const float4*)(in + (size_t)t0 * 8 + 4);
      xv.x = f2bf(A4.x) | ((unsigned)f2bf(A4.y) << 16);
      xv.y = f2bf(A4.z) | ((unsigned)f2bf(A4.w) << 16);
      xv.z = f2bf(B4.x) | ((unsigned)f2bf(B4.y) << 16);
      xv.w = f2bf(B4.z) | ((unsigned)f2bf(B4.w) << 16);
    }
    *(uint4*)(x0 + (size_t)c * rowstride) = xv;
  }
}

// ---- output rows 1024..1031 = inputs^T (exact fp32 copy) ----
__global__ void k_xrows(const float* __restrict__ in, float* __restrict__ out){
  int t = blockIdx.x * 256 + threadIdx.x;
  const float4 a = *(const float4*)(in + (size_t)t * 8);
  const float4 b = *(const float4*)(in + (size_t)t * 8 + 4);
  out[(size_t)(R_DIM + 0) * T_LEN + t] = a.x;
  out[(size_t)(R_DIM + 1) * T_LEN + t] = a.y;
  out[(size_t)(R_DIM + 2) * T_LEN + t] = a.z;
  out[(size_t)(R_DIM + 3) * T_LEN + t] = a.w;
  out[(size_t)(R_DIM + 4) * T_LEN + t] = b.x;
  out[(size_t)(R_DIM + 5) * T_LEN + t] = b.y;
  out[(size_t)(R_DIM + 6) * T_LEN + t] = b.z;
  out[(size_t)(R_DIM + 7) * T_LEN + t] = b.w;
}

// ---- hist[t][r] (bf16) -> out[r][t] (f32), tiled transpose ----
__global__ void k_transpose(const short* __restrict__ hist, float* __restrict__ out){
  __shared__ float tile[64][65];
  const int t0 = blockIdx.x * 64;
  const int r0 = blockIdx.y * 64;
  for (int it = 0; it < 2; ++it){
    int id = it * 256 + threadIdx.x;     // 512 chunks of 8 bf16
    int tr = id >> 3;
    int c8 = (id & 7) * 8;
    short8 v = *(const short8*)(hist + (size_t)(t0 + tr) * KE + r0 + c8);
    #pragma unroll
    for (int j = 0; j < 8; ++j){
      unsigned u = ((unsigned)(unsigned short)v[j]) << 16;
      tile[tr][c8 + j] = __builtin_bit_cast(float, u);
    }
  }
  __syncthreads();
  #pragma unroll
  for (int p = 0; p < 16; ++p){
    int rr = (threadIdx.x >> 6) + p * 4;
    int tc = threadIdx.x & 63;
    out[(size_t)(r0 + rr) * T_LEN + t0 + tc] = tile[tc][rr];
  }
}

#define MFMA16(a,b,c) __builtin_amdgcn_mfma_f32_16x16x32_bf16(a,b,c,0,0,0)

// issue 8 staging loads, NO wait (prefix p, pointer sp in scope)
#define STAGE8I(p, sfx) \
  asm volatile( \
    "global_load_dwordx4 %0, %8, off " sfx "\n\t" \
    "global_load_dwordx4 %1, %8, off offset:256 " sfx "\n\t" \
    "global_load_dwordx4 %2, %8, off offset:512 " sfx "\n\t" \
    "global_load_dwordx4 %3, %8, off offset:768 " sfx "\n\t" \
    "global_load_dwordx4 %4, %8, off offset:1024 " sfx "\n\t" \
    "global_load_dwordx4 %5, %8, off offset:1280 " sfx "\n\t" \
    "global_load_dwordx4 %6, %8, off offset:1536 " sfx "\n\t" \
    "global_load_dwordx4 %7, %8, off offset:1792 " sfx \
    : "=&v"(p##0),"=&v"(p##1),"=&v"(p##2),"=&v"(p##3), \
      "=&v"(p##4),"=&v"(p##5),"=&v"(p##6),"=&v"(p##7) \
    : "v"(sp) : "memory")

#define LDSW8(p, dst) do { \
  *(u32x4*)(dst + ((skb0 +    0) ^ sswz)) = p##0; \
  *(u32x4*)(dst + ((skb0 +  256) ^ sswz)) = p##1; \
  *(u32x4*)(dst + ((skb0 +  512) ^ sswz)) = p##2; \
  *(u32x4*)(dst + ((skb0 +  768) ^ sswz)) = p##3; \
  *(u32x4*)(dst + ((skb0 + 1024) ^ sswz)) = p##4; \
  *(u32x4*)(dst + ((skb0 + 1280) ^ sswz)) = p##5; \
  *(u32x4*)(dst + ((skb0 + 1536) ^ sswz)) = p##6; \
  *(u32x4*)(dst + ((skb0 + 1792) ^ sswz)) = p##7; } while(0)

// tail loads for col-tile ct -> u64 pair (issued early, drained by vmcnt(0))
#define TAILCT(ta, tb, ct) do{ \
  const char* tp = (const char*)(browf(colbase + (ct) * 16 + l15, k) + 1024 + l4 * 8); \
  asm volatile("global_load_dwordx2 %0, %2, off sc0 sc1\n\t" \
               "global_load_dwordx2 %1, %2, off offset:8 sc0 sc1" \
               : "=&v"(ta), "=&v"(tb) : "v"(tp) : "memory"); \
}while(0)

#define TAILMFMA(ta, tb, ct) do{ \
  u32x4 v_; v_.x=(unsigned)(ta); v_.y=(unsigned)((ta)>>32); \
            v_.z=(unsigned)(tb); v_.w=(unsigned)((tb)>>32); \
  const short8 b_ = __builtin_bit_cast(short8, v_); \
  acc0[ct] = MFMA16(a0[15], b_, acc0[ct]); \
  acc1[ct] = MFMA16(a1[15], b_, acc1[ct]); \
}while(0)

// ---- main: 256 WGs x 512 thr (1 WG/CU); WG = 128 rows x 64 cols, ONE phase.
// The per-step protocol chain (poll RT -> stage RT -> compute -> drain RT ->
// flag) is ~80% of step time (R7/R8 decomposition); paying it once per 64
// cols instead of twice is the lever. Stage = 16 loads (two 8-reg batches)
// issued back-to-back, single absolute vmcnt(0)+sched_barrier(0) (R12 lesson:
// counted vmcnt breaks under compiler VMEM). All cross-WG protocol sc0 sc1
// (R9/R10: L2-local sync nonviable); write-once rows (k>WARM+2) plain-cached
// (R7-proven). LB(512,1) = no-spill regime. A-frags are compiler-managed
// (R13 finding: never resident due to "memory" clobbers; L1/L2 reloads are
// cheap - do not fight it).
template<bool HIST>
__global__ __launch_bounds__(512, 1)
void k_esn(const float* __restrict__ inputs, const short* __restrict__ Wext,
           short* __restrict__ S0, short* __restrict__ S1,
           short* __restrict__ hist, unsigned* __restrict__ cnt,
           float* __restrict__ out)
{
  extern __shared__ __align__(16) char lds[];   // 64 cols x 2048B, XOR-swizzled
  const int tid  = threadIdx.x;
  const int g    = blockIdx.x & (NGRP - 1);
  const int rwg  = blockIdx.x >> 5;           // bid=rwg*32+g -> group on one XCD
  const int wv   = tid >> 6;
  const int lane = tid & 63;
  const int l15  = lane & 15, l4 = lane >> 4;
  const int hi   = wv & 1;
  const int rbase = rwg * 128 + (wv >> 1) * 32;
  const int colbase = g * WGC;
  unsigned* gflags = cnt + g * 16;            // 8 flags in one 64B line

  auto browf = [&](int col, int k) -> const short* {
    if (HIST){
      size_t row = (k <= WARM) ? ((size_t)col * LCH + ((k + 1) & 1))
                               : ((size_t)col * LCH + (size_t)(k - WARM) - 1);
      return hist + row * KE;
    }
    return ((k & 1) ? S1 : S0) + (size_t)col * KE;
  };
  auto wrowf = [&](int col, int k) -> short* {
    if (HIST){
      size_t row = (k < WARM) ? ((size_t)col * LCH + (k & 1))
                              : ((size_t)col * LCH + (size_t)(k - WARM));
      return hist + row * KE;
    }
    return ((k & 1) ? S0 : S1) + (size_t)col * KE;
  };

  // ---- A fragments (compiler-managed residency; R8's proven K-split) ----
  const int NA = hi ? 16 : 17;
  const int KB = hi ? 17 : 0;
  const int NL = hi ? 15 : 17;
  short8 a0[17], a1[17];
  {
    const short* abase = Wext + (size_t)(rbase + l15) * KE + l4 * 8;
    #pragma unroll
    for (int i = 0; i < 17; ++i){
      if (i < NA){
        const short* ap = abase + (KB + i) * 32;
        a0[i] = *(const short8*)ap;
        a1[i] = *(const short8*)(ap + (size_t)16 * KE);
      }
    }
  }

  const int scol = tid >> 4;                  // col 0..31 (and scol+32)
  const int skb0 = (tid & 15) << 4;
  const int sswz = (scol & 7) << 4;           // same for scol+32
  const int colb0 = l15 * 2048;
  const int bswz  = (l15 & 7) << 4;
  const int l4b   = l4 * 16;
  const int xsw = (lane * 16) ^ ((lane >> 3) << 4);

  for (int k = 0; k < STEPS; ++k){
    const bool coh = (!HIST) || (k <= WARM + 2);

    // ---- wait for all 8 producers (one flag-line RT; wv0 lanes 0..7) ----
    if (k > 0){
      if (wv == 0){
        const unsigned* fp = gflags + (lane & 7);
        int guard = 0;
        for (;;){
          unsigned pv;
          asm volatile("global_load_dword %0, %1, off sc0 sc1\n\t"
                       "s_waitcnt vmcnt(0)" : "=v"(pv) : "v"(fp) : "memory");
          if (!__any((int)(pv < (unsigned)k))) break;
          __builtin_amdgcn_s_sleep(1);
          if (++guard > 1000000) break;      // failsafe: degrade, don't hang
        }
      }
      __syncthreads();                        // A
    }

    // ---- issue K-ext tail loads (hi waves: 4 col-tiles) ----
    unsigned long long tq0=0,tq1=0,tq2=0,tq3=0,tq4=0,tq5=0,tq6=0,tq7=0;
    if (hi){
      TAILCT(tq0, tq1, 0); TAILCT(tq2, tq3, 1);
      TAILCT(tq4, tq5, 2); TAILCT(tq6, tq7, 3);
    }

    // ---- issue all 16 staging loads back-to-back (64 cols, 128KB) ----
    u32x4 ar0,ar1,ar2,ar3,ar4,ar5,ar6,ar7;
    u32x4 br0,br1,br2,br3,br4,br5,br6,br7;
    {
      const char* sp = (const char*)browf(colbase + scol, k) + skb0;
      if (coh) STAGE8I(ar, "sc0 sc1"); else STAGE8I(ar, "");
    }
    {
      const char* sp = (const char*)browf(colbase + scol + 32, k) + skb0;
      if (coh) STAGE8I(br, "sc0 sc1"); else STAGE8I(br, "");
    }

    // ---- single absolute drain; fence hoisting (rule #18) ----
    asm volatile("s_waitcnt vmcnt(0)" ::: "memory");
    __builtin_amdgcn_sched_barrier(0);
    LDSW8(ar, (&lds[scol * 2048]));
    LDSW8(br, (&lds[(scol + 32) * 2048]));
    __syncthreads();                          // B: 64-col tile staged

    // ---- MFMA K-loop over 4 col-tiles ----
    f32x4 acc0[4], acc1[4];
    #pragma unroll
    for (int ct = 0; ct < 4; ++ct){ acc0[ct] = f32x4{0,0,0,0}; acc1[ct] = f32x4{0,0,0,0}; }
    #pragma unroll
    for (int i = 0; i < 17; ++i){
      if (i < NL){
        int kb = (KB + i) * 64 + l4b;
        #pragma unroll
        for (int ct = 0; ct < 4; ++ct){
          const short8 b = *(const short8*)(&lds[colb0 + ct * 32768 + (kb ^ bswz)]);
          acc0[ct] = MFMA16(a0[i], b, acc0[ct]);
          acc1[ct] = MFMA16(a1[i], b, acc1[ct]);
        }
      }
    }
    if (hi){   // kk=32 tail: B from registers (pad nulled by Wext zeros)
      TAILMFMA(tq0, tq1, 0); TAILMFMA(tq2, tq3, 1);
      TAILMFMA(tq4, tq5, 2); TAILMFMA(tq6, tq7, 3);
    }

    // ---- cross-pair K-reduction via LDS (reuse staged region) ----
    __syncthreads();                          // C
    #pragma unroll
    for (int ct = 0; ct < 4; ++ct)
      *(f32x4*)(&lds[ct * 8192 + wv * 1024 + xsw]) = hi ? acc0[ct] : acc1[ct];
    __syncthreads();                          // D
    {
      const int rowb = rbase + hi * 16 + l4 * 4;
      #pragma unroll
      for (int ct = 0; ct < 4; ++ct){
        f32x4 p = *(const f32x4*)(&lds[ct * 8192 + (wv ^ 1) * 1024 + xsw]);
        f32x4 z = (hi ? acc1[ct] : acc0[ct]) + p;
        float s0 = fast_tanh(z[0]), s1 = fast_tanh(z[1]);
        float s2 = fast_tanh(z[2]), s3 = fast_tanh(z[3]);
        unsigned long long pk = (unsigned long long)f2bf(s0)
          | ((unsigned long long)f2bf(s1) << 16)
          | ((unsigned long long)f2bf(s2) << 32)
          | ((unsigned long long)f2bf(s3) << 48);
        int col = colbase + ct * 16 + l15;
        short* wp = wrowf(col, k) + rowb;
        asm volatile("global_store_dwordx2 %0, %1, off sc0 sc1"
                     :: "v"(wp), "v"(pk) : "memory");
        if (!HIST && k >= WARM){
          int tk = col * LCH + k - WARM;
          float* op = out + (size_t)rowb * T_LEN + tk;
          op[0] = s0; op[(size_t)T_LEN] = s1;
          op[(size_t)2 * T_LEN] = s2; op[(size_t)3 * T_LEN] = s3;
        }
      }
    }

    // ---- x for next step (rwg0, all 64 cols) ----
    if (rwg == 0 && tid < WGC && (k + 1) < STEPS){
      int col = colbase + tid;
      short* xr = wrowf(col, k) + 1024;
      int tn = col * LCH + (k + 1) - WARM;
      u32x4 xv = {0,0,0,0};
      if (tn >= 0){
        const float4 A4 = *(const float4*)(inputs + (size_t)tn * 8);
        const float4 B4 = *(const float4*)(inputs + (size_t)tn * 8 + 4);
        xv.x = f2bf(A4.x) | ((unsigned)f2bf(A4.y) << 16);
        xv.y = f2bf(A4.z) | ((unsigned)f2bf(A4.w) << 16);
        xv.z = f2bf(B4.x) | ((unsigned)f2bf(B4.y) << 16);
        xv.w = f2bf(B4.z) | ((unsigned)f2bf(B4.w) << 16);
      }
      asm volatile("global_store_dwordx4 %0, %1, off sc0 sc1"
                   :: "v"(xr), "v"(xv) : "memory");
    }

    // ---- drain own stores to coherence point, then signal ----
    asm volatile("s_waitcnt vmcnt(0)" ::: "memory");
    __syncthreads();                          // E (all waves drained)
    if (tid == 0 && (k + 1) < STEPS){
      unsigned* fw = gflags + rwg;
      unsigned fv = (unsigned)(k + 1);
      asm volatile("global_store_dword %0, %1, off sc0 sc1"
                   :: "v"(fw), "v"(fv) : "memory");
    }
  }
}

extern "C" void kernel_launch(void* const* d_in, const int* in_sizes, int n_in,
                              void* d_out, int out_size, void* d_ws, size_t ws_size,
                              hipStream_t stream)
{
  (void)in_sizes; (void)n_in; (void)out_size;
  const float* inputs = (const float*)d_in[0];
  const float* Win    = (const float*)d_in[1];
  const float* Wres   = (const float*)d_in[2];
  float* out = (float*)d_out;
  char* ws = (char*)d_ws;

  short*    Wext = (short*)(ws);                       // 2,162,688 B
  unsigned* cnt  = (unsigned*)(ws + 2162688);          // 32 groups x 64B
  char*     data = ws + 2166784;
  short*    hist = (short*)data;                       // 65536*1056*2 = 138,412,032 B
  short*    S0   = (short*)data;                       // !HIST: 2048*1056*2 B
  short*    S1   = (short*)(data + 4325376);
  const bool hist_ok = ws_size >= (2166784ull + 138412032ull);

  hipLaunchKernelGGL(k_build_wext, dim3(4224), dim3(256), 0, stream, Wres, Win, Wext);
  hipLaunchKernelGGL(k_xrows,      dim3(256),  dim3(256), 0, stream, inputs, out);
  if (hist_ok){
    hipLaunchKernelGGL(k_zero_init, dim3(4096), dim3(256), 0, stream,
                       hist + KE, (size_t)LCH * KE);
    hipLaunchKernelGGL(k_init_x,    dim3(8),    dim3(256), 0, stream,
                       inputs, hist + KE + 1024, (size_t)LCH * KE, cnt);
    hipLaunchKernelGGL((k_esn<true>),  dim3(RWG * NGRP), dim3(512), LDSB, stream,
                       inputs, Wext, S0, S1, hist, cnt, out);
    hipLaunchKernelGGL(k_transpose, dim3(1024, 16), dim3(256), 0, stream, hist, out);
  } else {
    hipLaunchKernelGGL(k_zero_init, dim3(4096), dim3(256), 0, stream,
                       S0, (size_t)KE);
    hipLaunchKernelGGL(k_init_x,    dim3(8),    dim3(256), 0, stream,
                       inputs, S0 + 1024, (size_t)KE, cnt);
    hipLaunchKernelGGL((k_esn<false>), dim3(RWG * NGRP), dim3(512), LDSB, stream,
                       inputs, Wext, S0, S1, hist, cnt, out);
  }
}